// Round 7
// baseline (452.133 us; speedup 1.0000x reference)
//
#include <hip/hip_runtime.h>
#include <math.h>

#define NPIX 4096
#define BATCH 32
#define CDIM 256
#define SCALE_F 0.17677669529663687f   // 32^-0.5
#define EPS_F 1e-5f

typedef _Float16 f16;
typedef _Float16 f16x8 __attribute__((ext_vector_type(8)));
typedef _Float16 f16x4 __attribute__((ext_vector_type(4)));
typedef float    f32x4 __attribute__((ext_vector_type(4)));

static __device__ __forceinline__ f32x4 mfma16(f16x8 a, f16x8 b, f32x4 c) {
    return __builtin_amdgcn_mfma_f32_16x16x32_f16(a, b, c, 0, 0, 0);
}

// ---------------------------------------------------------------------------
// K0: w_qkv (384x256 fp32) -> wh (f16), row-major (r2-verified layout)
// ---------------------------------------------------------------------------
__global__ __launch_bounds__(256)
void wconv(const float* __restrict__ w, f16* __restrict__ wh)
{
    int i = blockIdx.x * 256 + threadIdx.x;      // 24576 float4 groups
    float4 v = ((const float4*)w)[i];
    f16x4 o = {(f16)v.x, (f16)v.y, (f16)v.z, (f16)v.w};
    ((f16x4*)wh)[i] = o;
}

// ---------------------------------------------------------------------------
// K1: x[b][k][n] fp32 -> xt[z][n][k] f16   (64x64 tiles, 16 batches/phase)
//  Round-0-verified kernel, verbatim.
// ---------------------------------------------------------------------------
__global__ __launch_bounds__(256)
void transpose_x(const float* __restrict__ x, f16* __restrict__ xt, int b0)
{
    __shared__ f16 T[64][66];
    const int b = b0 + blockIdx.z;
    const int n0 = blockIdx.x * 64, k0 = blockIdx.y * 64;
    const float* xb = x + ((size_t)b * 256 + k0) * NPIX + n0;
    const int t = threadIdx.x;
    const int kl = t >> 2;
    #pragma unroll
    for (int it = 0; it < 4; it++) {
        int nq = (t & 3) + it * 4;               // 0..15
        float4 v = *(const float4*)&xb[(size_t)kl * NPIX + nq * 4];
        T[kl][nq * 4 + 0] = (f16)v.x;
        T[kl][nq * 4 + 1] = (f16)v.y;
        T[kl][nq * 4 + 2] = (f16)v.z;
        T[kl][nq * 4 + 3] = (f16)v.w;
    }
    __syncthreads();
    const int nl = t >> 2, kc = t & 3;
    f16 tmp[16];
    #pragma unroll
    for (int j = 0; j < 16; j++) tmp[j] = T[kc * 16 + j][nl];
    f16* dst = xt + ((size_t)blockIdx.z * NPIX + n0 + nl) * 256 + k0 + kc * 16;
    *(f16x8*)dst = *(f16x8*)&tmp[0];
    *(f16x8*)(dst + 8) = *(f16x8*)&tmp[8];
}

// ---------------------------------------------------------------------------
// K2: FUSED qkv GEMM (M=384, N=64/tile x2 tiles, K=256) from f16 xt.
//  r2-verified structure (133 us) with the x-fp32 scalar path removed:
//  B-staging = ONE f16x8 load/thread/k-step from xt (no cvt, 1 prefetch reg).
//  A-staging/swizzles/epilogue/ctx-MFMA byte-identical to r2; ksum via LDS
//  (r5-verified). Grid (32 ngroups, 16 batches)/phase = 512 blocks, 4 waves.
// ---------------------------------------------------------------------------
__global__ __launch_bounds__(256)
void qkv_fused(const f16* __restrict__ wh, const f16* __restrict__ xt, int b0,
               f16* __restrict__ qhatT, float* __restrict__ ctx,
               float* __restrict__ ksum)
{
    __shared__ __align__(16) f16 As[384 * 32];   // 24 KB, XOR-swizzled chunks
    __shared__ __align__(16) f16 Bs[64 * 32];    //  4 KB, XOR-swizzled chunks
    __shared__ __align__(16) f16 ek_s[128 * 64]; // 16 KB, XOR-swizzled chunks
    __shared__ __align__(16) f16 v_s[128 * 64];  // 16 KB
    __shared__ float ksum_s[128];                // 512 B (total ~60.5 KB)

    const int z = blockIdx.y;                    // batch within phase
    const int b = b0 + z;
    const int t = threadIdx.x;
    const int lane = t & 63, w = t >> 6;
    const int lane15 = lane & 15, lg = lane >> 4;
    const int grow = w * 96;

    const f16* xtb = xt + (size_t)z * NPIX * 256;
    f16* qT = qhatT + (size_t)b * NPIX * 128;

    // B staging: thread t packs 8 k-values (chunk bc) of pixel bn
    const int bn = t & 63;
    const int bc = t >> 6;
    const int bsw = bn * 32 + ((bc ^ ((bn >> 1) & 3)) << 3);

    if (t < 128) ksum_s[t] = 0.f;

    f32x4 ctxacc[2][2];
    const f32x4 z4 = {0.f, 0.f, 0.f, 0.f};
    ctxacc[0][0] = z4; ctxacc[0][1] = z4; ctxacc[1][0] = z4; ctxacc[1][1] = z4;

    for (int tile = 0; tile < 2; tile++) {
        const int n0 = blockIdx.x * 128 + tile * 64;
        f32x4 acc[6][4];
        #pragma unroll
        for (int i = 0; i < 6; i++)
            #pragma unroll
            for (int j = 0; j < 4; j++) acc[i][j] = z4;

        // preload B for ks=0: one 16B f16x8 per thread
        f16x8 bv = *(const f16x8*)&xtb[(size_t)(n0 + bn) * 256 + bc * 8];

        for (int k0 = 0; k0 < 256; k0 += 32) {
            // A staging (r2-verified strided reads, swizzled LDS writes)
            #pragma unroll
            for (int it = 0; it < 6; it++) {
                int c = t + it * 256;            // 1536 x 16B chunks per panel
                int row = c >> 2, ch = c & 3;
                *(f16x8*)&As[row * 32 + ((ch ^ ((row >> 1) & 3)) << 3)] =
                    *(const f16x8*)&wh[(size_t)row * 256 + k0 + ch * 8];
            }
            // B staging: one swizzled b128 write (no cvt)
            *(f16x8*)&Bs[bsw] = bv;
            __syncthreads();
            // prefetch next k-step's B under the MFMA phase
            if (k0 < 224)
                bv = *(const f16x8*)&xtb[(size_t)(n0 + bn) * 256 + k0 + 32 + bc * 8];
            f16x8 af[6], bf[4];
            #pragma unroll
            for (int j = 0; j < 4; j++) {
                int rr = j * 16 + lane15;
                bf[j] = *(const f16x8*)&Bs[rr * 32 + ((lg ^ ((rr >> 1) & 3)) << 3)];
            }
            #pragma unroll
            for (int i = 0; i < 6; i++) {
                int rr = grow + i * 16 + lane15;
                af[i] = *(const f16x8*)&As[rr * 32 + ((lg ^ ((rr >> 1) & 3)) << 3)];
            }
            #pragma unroll
            for (int i = 0; i < 6; i++)
                #pragma unroll
                for (int j = 0; j < 4; j++)
                    acc[i][j] = mfma16(af[i], bf[j], acc[i][j]);
            __syncthreads();
        }

        // ---- epilogue: classify fragments by global row (verified r2) ----
        #pragma unroll
        for (int i = 0; i < 6; i++) {
            const int rbase = grow + i * 16;
            if (rbase < 128) {
                if ((rbase & 31) == 0) {
                    // q head (frags i, i+1): softmax over d (32 rows) per pixel
                    #pragma unroll
                    for (int j = 0; j < 4; j++) {
                        float e0[2][4]; float s = 0.f;
                        #pragma unroll
                        for (int ii = 0; ii < 2; ii++)
                            #pragma unroll
                            for (int r = 0; r < 4; r++) {
                                float ev = __expf(acc[i + ii][j][r]);
                                e0[ii][r] = ev; s += ev;
                            }
                        s += __shfl_xor(s, 16); s += __shfl_xor(s, 32);
                        float inv = SCALE_F / s;
                        int n = n0 + j * 16 + lane15;
                        #pragma unroll
                        for (int ii = 0; ii < 2; ii++) {
                            int d0 = rbase + ii * 16 + lg * 4;
                            f16x4 pk;
                            #pragma unroll
                            for (int r = 0; r < 4; r++) pk[r] = (f16)(e0[ii][r] * inv);
                            *(f16x4*)(qT + (size_t)n * 128 + d0) = pk;
                        }
                    }
                }
            } else if (rbase < 256) {
                // k frag: ek=exp(k) -> LDS, row-sum -> ksum_s (LDS atomic)
                const int kb = rbase - 128;
                #pragma unroll
                for (int r = 0; r < 4; r++) {
                    int row = kb + lg * 4 + r;
                    float p = 0.f;
                    #pragma unroll
                    for (int j = 0; j < 4; j++) {
                        float ev = __expf(acc[i][j][r]);
                        p += ev;
                        int col = j * 16 + lane15;
                        ek_s[row * 64 + ((((col >> 3) ^ (row & 7)) << 3) | (col & 7))] =
                            (f16)ev;
                    }
                    p += __shfl_xor(p, 1); p += __shfl_xor(p, 2);
                    p += __shfl_xor(p, 4); p += __shfl_xor(p, 8);
                    if (lane15 == 0) atomicAdd(&ksum_s[row], p);
                }
            } else {
                // v frag -> LDS
                const int vb = rbase - 256;
                #pragma unroll
                for (int r = 0; r < 4; r++) {
                    int row = vb + lg * 4 + r;
                    #pragma unroll
                    for (int j = 0; j < 4; j++) {
                        int col = j * 16 + lane15;
                        v_s[row * 64 + ((((col >> 3) ^ (row & 7)) << 3) | (col & 7))] =
                            (f16)acc[i][j][r];
                    }
                }
            }
        }
        __syncthreads();
        // ctx partial for head w: 32x32 over K=n=64 (2 MFMA k-steps)
        #pragma unroll
        for (int ks2 = 0; ks2 < 2; ks2++) {
            f16x8 a2[2], b2[2];
            #pragma unroll
            for (int i2 = 0; i2 < 2; i2++) {
                int row = w * 32 + i2 * 16 + lane15;
                int off = row * 64 + (((ks2 * 4 + lg) ^ (row & 7)) << 3);
                a2[i2] = *(const f16x8*)&ek_s[off];
                b2[i2] = *(const f16x8*)&v_s[off];
            }
            #pragma unroll
            for (int i2 = 0; i2 < 2; i2++)
                #pragma unroll
                for (int j2 = 0; j2 < 2; j2++)
                    ctxacc[i2][j2] = mfma16(a2[i2], b2[j2], ctxacc[i2][j2]);
        }
        // next tile's k-loop barriers order these reads before ek_s/v_s rewrite
    }

    // ksum flush: one global atomic batch per block
    if (t < 128) atomicAdd(&ksum[b * 128 + t], ksum_s[t]);

    // ctx[bh][d][e] += partials (ctx is 512 KB, L2-resident)
    float* cg = ctx + ((size_t)b * 4 + w) * 1024;
    #pragma unroll
    for (int i2 = 0; i2 < 2; i2++)
        #pragma unroll
        for (int j2 = 0; j2 < 2; j2++)
            #pragma unroll
            for (int r = 0; r < 4; r++)
                atomicAdd(&cg[(i2 * 16 + lg * 4 + r) * 32 + j2 * 16 + lane15],
                          ctxacc[i2][j2][r]);
}

// ---------------------------------------------------------------------------
// K4: W_eff[b][o][h*32+d] = sum_e w_out[o][h*32+e] * ctx[b,h,d,e]/ksum[d] (f16)
// ---------------------------------------------------------------------------
__global__ __launch_bounds__(256)
void weff_kernel(const float* __restrict__ wout, const float* __restrict__ ctx,
                 const float* __restrict__ ksum, f16* __restrict__ weff)
{
    const int bh = blockIdx.x;                  // 0..127
    const int b = bh >> 2, h = bh & 3;
    __shared__ float cs[1024];
    __shared__ float inv_s[32];
    const int t = threadIdx.x;                  // t = output channel o
    for (int i = t; i < 1024; i += 256) cs[i] = ctx[(size_t)bh * 1024 + i];
    if (t < 32) inv_s[t] = 1.f / ksum[b * 128 + h * 32 + t];
    __syncthreads();
    float acc[32] = {};
    const float* wrow = wout + (size_t)t * 128 + h * 32;
    for (int e = 0; e < 32; e++) {
        float wv = wrow[e];
        #pragma unroll
        for (int d = 0; d < 32; d++) acc[d] += wv * cs[d * 32 + e];
    }
    f16* wo = weff + ((size_t)b * 256 + t) * 128 + h * 32;
    #pragma unroll
    for (int d = 0; d < 32; d++) wo[d] = (f16)(acc[d] * inv_s[d]);
}

// ---------------------------------------------------------------------------
// K5: out = LN(weff[b](256x128) @ qhatT^T + b_out)*g + b ; MFMA, 256x128 tile.
// ---------------------------------------------------------------------------
__global__ __launch_bounds__(256)
void out_mfma_ln(const f16* __restrict__ weff, const f16* __restrict__ qhatT,
                 const float* __restrict__ bias, const float* __restrict__ g,
                 const float* __restrict__ bb, float* __restrict__ out)
{
    __shared__ __align__(16) f16 As2[256 * 32];   // 16 KB
    __shared__ __align__(16) f16 Bs2[128 * 32];   // 8 KB
    __shared__ float pb[256], pg[256], pbb[256];
    __shared__ float lds_s[4][128], lds_s2[4][128];
    const int b = blockIdx.y;
    const int tileN = blockIdx.x * 128;
    const int t = threadIdx.x;
    const int lane = t & 63, w = t >> 6;
    const int lane15 = lane & 15, lg = lane >> 4;
    pb[t] = bias[t]; pg[t] = g[t]; pbb[t] = bb[t];
    const f16* Aw = weff + (size_t)b * 256 * 128;
    const f16* Bw = qhatT + (size_t)b * NPIX * 128;
    f32x4 acc[4][8];
    const f32x4 z4 = {0.f, 0.f, 0.f, 0.f};
    #pragma unroll
    for (int i = 0; i < 4; i++)
        #pragma unroll
        for (int j = 0; j < 8; j++) acc[i][j] = z4;

    for (int k0 = 0; k0 < 128; k0 += 32) {
        #pragma unroll
        for (int it = 0; it < 4; it++) {         // A: 1024 x 16B chunks
            int c = t + it * 256;
            int row = c >> 2, koff = (c & 3) * 8;
            *(f16x8*)&As2[row * 32 + koff] = *(const f16x8*)&Aw[(size_t)row * 128 + k0 + koff];
        }
        #pragma unroll
        for (int it = 0; it < 2; it++) {         // B: 512 x 16B chunks
            int c = t + it * 256;
            int row = c >> 2, koff = (c & 3) * 8;
            *(f16x8*)&Bs2[row * 32 + koff] =
                *(const f16x8*)&Bw[(size_t)(tileN + row) * 128 + k0 + koff];
        }
        __syncthreads();
        f16x8 af[4], bf[8];
        #pragma unroll
        for (int i = 0; i < 4; i++)
            af[i] = *(const f16x8*)&As2[(w * 64 + i * 16 + lane15) * 32 + lg * 8];
        #pragma unroll
        for (int j = 0; j < 8; j++)
            bf[j] = *(const f16x8*)&Bs2[(j * 16 + lane15) * 32 + lg * 8];
        #pragma unroll
        for (int i = 0; i < 4; i++)
            #pragma unroll
            for (int j = 0; j < 8; j++)
                acc[i][j] = mfma16(af[i], bf[j], acc[i][j]);
        __syncthreads();
    }
    // + bias
    #pragma unroll
    for (int i = 0; i < 4; i++)
        #pragma unroll
        for (int r = 0; r < 4; r++) {
            float bo = pb[w * 64 + i * 16 + lg * 4 + r];
            #pragma unroll
            for (int j = 0; j < 8; j++) acc[i][j][r] += bo;
        }
    // per-column stats (over this wave's 64 rows), then cross-wave via LDS
    #pragma unroll
    for (int j = 0; j < 8; j++) {
        float s = 0.f, s2 = 0.f;
        #pragma unroll
        for (int i = 0; i < 4; i++)
            #pragma unroll
            for (int r = 0; r < 4; r++) { float v = acc[i][j][r]; s += v; s2 += v * v; }
        s += __shfl_xor(s, 16);  s += __shfl_xor(s, 32);
        s2 += __shfl_xor(s2, 16); s2 += __shfl_xor(s2, 32);
        if (lg == 0) { lds_s[w][j * 16 + lane15] = s; lds_s2[w][j * 16 + lane15] = s2; }
    }
    __syncthreads();
    float mean[8], rstd[8];
    #pragma unroll
    for (int j = 0; j < 8; j++) {
        int col = j * 16 + lane15;
        float S = lds_s[0][col] + lds_s[1][col] + lds_s[2][col] + lds_s[3][col];
        float S2 = lds_s2[0][col] + lds_s2[1][col] + lds_s2[2][col] + lds_s2[3][col];
        float mn = S * (1.f / 256.f);
        mean[j] = mn;
        rstd[j] = rsqrtf(S2 * (1.f / 256.f) - mn * mn + EPS_F);
    }
    float* ob = out + (size_t)b * CDIM * NPIX;
    #pragma unroll
    for (int i = 0; i < 4; i++)
        #pragma unroll
        for (int r = 0; r < 4; r++) {
            int row = w * 64 + i * 16 + lg * 4 + r;
            float gm = pg[row], bt = pbb[row];
            #pragma unroll
            for (int j = 0; j < 8; j++)
                ob[(size_t)row * NPIX + tileN + j * 16 + lane15] =
                    (acc[i][j][r] - mean[j]) * rstd[j] * gm + bt;
        }
}

extern "C" void kernel_launch(void* const* d_in, const int* in_sizes, int n_in,
                              void* d_out, int out_size, void* d_ws, size_t ws_size,
                              hipStream_t stream)
{
    const float* x     = (const float*)d_in[0];
    const float* w_qkv = (const float*)d_in[1];
    const float* w_out = (const float*)d_in[2];
    const float* b_out = (const float*)d_in[3];
    const float* g     = (const float*)d_in[4];
    const float* bvec  = (const float*)d_in[5];
    float* out = (float*)d_out;

    // ws layout (bytes), total 69,943,296 B = 66.7 MiB (r0-proven layout):
    char* wsb = (char*)d_ws;
    f16*   xt    = (f16*)wsb;                    // 33,554,432 (16 batches/phase)
    f16*   qhatT = (f16*)(wsb + 33554432);       // 33,554,432
    float* ctx   = (float*)(wsb + 67108864);     //    524,288
    float* ksum  = (float*)(wsb + 67633152);     //     16,384
    f16*   weff  = (f16*)(wsb + 67649536);       //  2,097,152
    f16*   wh    = (f16*)(wsb + 69746688);       //    196,608

    hipMemsetAsync(ctx, 0, 540672, stream);      // ctx + ksum (adjacent)
    wconv<<<96, 256, 0, stream>>>(w_qkv, wh);
    for (int p = 0; p < 2; p++) {
        transpose_x<<<dim3(64, 4, 16), 256, 0, stream>>>(x, xt, p * 16);
        qkv_fused<<<dim3(32, 16), 256, 0, stream>>>(wh, xt, p * 16,
                                                    qhatT, ctx, ksum);
    }
    weff_kernel<<<128, 256, 0, stream>>>(w_out, ctx, ksum, weff);
    out_mfma_ln<<<dim3(32, BATCH), 256, 0, stream>>>(weff, qhatT, b_out, g, bvec, out);
}